// Round 8
// baseline (441.523 us; speedup 1.0000x reference)
//
#include <hip/hip_runtime.h>
#include <hip/hip_bf16.h>
#include <stdint.h>

#define NNODES 100000
#define DF 64
#define NEDGES 1600000
#define ND (NNODES * DF)     // 6,400,000
#define BKT 100              // targets per bucket
#define NBUCK 1000           // BKT*NBUCK == NNODES
#define CHUNK 128            // edges per wave in agg_k
#define NCHUNK (NEDGES / CHUNK)   // 12500
#define NWTILE (NNODES / 16) // 6250 MFMA wave-tiles

typedef __attribute__((ext_vector_type(8))) short short8;
typedef __attribute__((ext_vector_type(4))) float f32x4;

// ---------- helpers ----------
static __device__ __forceinline__ float bf2f(unsigned short u) {
    union { uint32_t i; float f; } c; c.i = ((uint32_t)u) << 16; return c.f;
}
static __device__ __forceinline__ void unpack2(uint32_t u, float& lo, float& hi) {
    union { uint32_t i; float f; } a, b;
    a.i = u << 16; b.i = u & 0xFFFF0000u;
    lo = a.f; hi = b.f;
}

// ---------- dtype detector: flags[0]=bf16?, flags[1]=int64? ----------
__global__ void detect_k(const unsigned short* __restrict__ x,
                         const unsigned int* __restrict__ ei,
                         int* __restrict__ flags) {
    __shared__ int cnt_sane, cnt_odd_nz;
    if (threadIdx.x == 0) { cnt_sane = 0; cnt_odd_nz = 0; }
    __syncthreads();
    unsigned short s = x[threadIdx.x * 2];
    unsigned short m = s & 0x7FFF;
    if (m < 0x0080 || (m >= 0x3000 && m <= 0x4200)) atomicAdd(&cnt_sane, 1);
    if (threadIdx.x < 64) {
        if (ei[threadIdx.x * 2 + 1] != 0u) atomicAdd(&cnt_odd_nz, 1);
    }
    __syncthreads();
    if (threadIdx.x == 0) {
        flags[0] = (cnt_sane >= 192) ? 1 : 0;
        flags[1] = (cnt_odd_nz == 0) ? 1 : 0;
    }
}

// ---------- weight canonicalization -> fp32 (fallback path + biases) ----------
__global__ void wconv_k(const int* __restrict__ flags,
                        const void* __restrict__ Wm, const void* __restrict__ Wu,
                        const void* __restrict__ bm, const void* __restrict__ bu,
                        const void* __restrict__ ga, const void* __restrict__ be,
                        float* __restrict__ WfM, float* __restrict__ WfU,
                        float* __restrict__ prm) {
    const int bf = flags[0];
    int i = blockIdx.x * 256 + threadIdx.x;
    if (i < 16384) {
        const void* src = (i < 8192) ? Wm : Wu;
        float* dst = (i < 8192) ? WfM : WfU;
        int ii = i & 8191, j = ii >> 6, k = ii & 63;
        int si = (j & 63) * 128 + ((j >> 6) ? 64 : 0) + k;
        dst[ii] = bf ? bf2f(((const unsigned short*)src)[si]) : ((const float*)src)[si];
    } else if (i < 16384 + 256) {
        int t = i - 16384, which = t >> 6, k = t & 63;
        const void* p = (which == 0) ? bm : (which == 1) ? bu : (which == 2) ? ga : be;
        prm[t] = bf ? bf2f(((const unsigned short*)p)[k]) : ((const float*)p)[k];
    }
}

// ---------- projection via MFMA: Ps = x@Wm_s^T ; Pt = x@Wm_t^T + b_msg ----------
// bf16 path: wave = 16 nodes, 8 coltiles of 16, K=64 (2 mfma each).
__global__ __launch_bounds__(256) void proj_k(const int* __restrict__ flags,
                                              const void* __restrict__ xv,
                                              const void* __restrict__ WmRaw,
                                              const float* __restrict__ WfM,
                                              const float* __restrict__ prm,
                                              __hip_bfloat16* __restrict__ Ps,
                                              __hip_bfloat16* __restrict__ Pt) {
    const int bf = flags[0];
    const int lane = threadIdx.x & 63;
    const int wib = __builtin_amdgcn_readfirstlane(threadIdx.x >> 6);

    if (bf) {
        const int w = blockIdx.x * 4 + wib;
        if (w >= NWTILE) return;
        const int node0 = w * 16;
        const int m = lane & 15, quad = lane >> 4;
        const unsigned short* x16 = (const unsigned short*)xv;
        const unsigned short* wm16 = (const unsigned short*)WmRaw;

        // A frags: A[m][k=quad*8+j], K chunks {0..31, 32..63}
        const short8 A0 = *(const short8*)(x16 + (size_t)(node0 + m) * 64 + quad * 8);
        const short8 A1 = *(const short8*)(x16 + (size_t)(node0 + m) * 64 + 32 + quad * 8);

        #pragma unroll
        for (int c = 0; c < 8; ++c) {
            const int j = (c & 3) * 16 + m;        // B row (out feature)
            const int koff = (c >> 2) * 64;        // 0 = Wm_s cols, 64 = Wm_t cols
            const short8 B0 = *(const short8*)(wm16 + j * 128 + koff + quad * 8);
            const short8 B1 = *(const short8*)(wm16 + j * 128 + koff + 32 + quad * 8);
            const float binit = (c < 4) ? 0.f : prm[(c - 4) * 16 + m];  // b_msg for Pt
            f32x4 acc;
            acc[0] = binit; acc[1] = binit; acc[2] = binit; acc[3] = binit;
            acc = __builtin_amdgcn_mfma_f32_16x16x32_bf16(A0, B0, acc, 0, 0, 0);
            acc = __builtin_amdgcn_mfma_f32_16x16x32_bf16(A1, B1, acc, 0, 0, 0);
            __hip_bfloat16* dst = (c < 4) ? Ps : Pt;
            const int colg = (c & 3) * 16 + m;     // D: col=lane&15
            #pragma unroll
            for (int r = 0; r < 4; ++r) {          // D: row=quad*4+reg
                const int node = node0 + quad * 4 + r;
                dst[(size_t)node * 64 + colg] = __float2bfloat16(acc[r]);
            }
        }
    } else {
        // fp32 fallback (VALU): lane=feature, node wave-uniform
        float wsr[64], wtr[64];
        const float* r0 = WfM + lane * 64;
        const float* r1 = WfM + (64 + lane) * 64;
        #pragma unroll
        for (int k = 0; k < 64; ++k) { wsr[k] = r0[k]; wtr[k] = r1[k]; }
        const float bm = prm[lane];
        for (int n = blockIdx.x * 4 + wib; n < NNODES; n += gridDim.x * 4) {
            float as = 0.f, at = 0.f;
            const float* xf = (const float*)xv + (size_t)n * DF;
            #pragma unroll
            for (int d = 0; d < 64; ++d) {
                as = fmaf(xf[d], wsr[d], as);
                at = fmaf(xf[d], wtr[d], at);
            }
            Ps[(size_t)n * DF + lane] = __float2bfloat16(as);
            Pt[(size_t)n * DF + lane] = __float2bfloat16(at + bm);
        }
    }
}

// ---------- bucket histogram (LDS pre-aggregated) ----------
__global__ __launch_bounds__(256) void bhist_k(const int* __restrict__ flags,
                                               const int* __restrict__ ei,
                                               int* __restrict__ BktCnt) {
    __shared__ int h[NBUCK];
    const int i64 = flags[1];
    for (int i = threadIdx.x; i < NBUCK; i += 256) h[i] = 0;
    __syncthreads();
    int stride = gridDim.x * 256;
    for (int e = blockIdx.x * 256 + threadIdx.x; e < NEDGES; e += stride) {
        int tgt = i64 ? ei[4*e + 2] : ei[2*e + 1];
        if ((unsigned)tgt < NNODES) atomicAdd(&h[tgt / BKT], 1);
    }
    __syncthreads();
    for (int b = threadIdx.x; b < NBUCK; b += 256)
        if (h[b]) atomicAdd(BktCnt + b, h[b]);
}

// ---------- scan of 1000 bucket counts ----------
__global__ __launch_bounds__(1024) void bscan_k(const int* __restrict__ BktCnt,
                                                int* __restrict__ BktOff,
                                                int* __restrict__ BktCur) {
    __shared__ int lds[1024];
    int t = threadIdx.x;
    int c = (t < NBUCK) ? BktCnt[t] : 0;
    lds[t] = c;
    __syncthreads();
    for (int off = 1; off < 1024; off <<= 1) {
        int add = (t >= off) ? lds[t - off] : 0;
        __syncthreads();
        lds[t] += add;
        __syncthreads();
    }
    if (t < NBUCK) {
        int ex = lds[t] - c;
        BktOff[t] = ex;
        BktCur[t] = ex;
    }
    if (t == NBUCK - 1) BktOff[NBUCK] = lds[t];
}

// ---------- bucket fill: two-pass binning, packed (tl<<24 | src) ----------
__global__ __launch_bounds__(256) void bfill_k(const int* __restrict__ flags,
                                               const int* __restrict__ ei,
                                               int* __restrict__ BktCur,
                                               int* __restrict__ BktE) {
    __shared__ int h[NBUCK], h2[NBUCK], basee[NBUCK];
    const int i64 = flags[1];
    for (int i = threadIdx.x; i < NBUCK; i += 256) { h[i] = 0; h2[i] = 0; }
    __syncthreads();
    const int stride = gridDim.x * 256;
    for (int e = blockIdx.x * 256 + threadIdx.x; e < NEDGES; e += stride) {
        int tgt = i64 ? ei[4*e + 2] : ei[2*e + 1];
        if ((unsigned)tgt < NNODES) atomicAdd(&h[tgt / BKT], 1);
    }
    __syncthreads();
    for (int b = threadIdx.x; b < NBUCK; b += 256)
        if (h[b]) basee[b] = atomicAdd(BktCur + b, h[b]);
    __syncthreads();
    for (int e = blockIdx.x * 256 + threadIdx.x; e < NEDGES; e += stride) {
        int src, tgt;
        if (i64) { src = ei[4*e]; tgt = ei[4*e + 2]; }
        else     { src = ei[2*e]; tgt = ei[2*e + 1]; }
        if ((unsigned)tgt >= NNODES) continue;
        int b = tgt / BKT;
        int tl = tgt - b * BKT;
        int r = atomicAdd(&h2[b], 1);
        BktE[basee[b] + r] = (tl << 24) | (src & 0xFFFFFF);
    }
}

// ---------- per-bucket counting sort by target -> CsrSrc + Row ----------
__global__ __launch_bounds__(256) void tsort_k(const int* __restrict__ BktOff,
                                               const int* __restrict__ BktE,
                                               int* __restrict__ CsrSrc,
                                               int* __restrict__ Row) {
    __shared__ int oc[128], excl[128], cur[128];
    const int tid = threadIdx.x;
    const int b = blockIdx.x;
    const int s = BktOff[b], e = BktOff[b + 1];
    const int n = e - s;
    if (tid < 128) { oc[tid] = 0; }
    __syncthreads();
    for (int i = tid; i < n; i += 256)
        atomicAdd(&oc[((unsigned)BktE[s + i]) >> 24], 1);
    __syncthreads();
    if (tid < 128) excl[tid] = (tid > 0) ? oc[tid - 1] : 0;
    __syncthreads();
    for (int off = 1; off < 128; off <<= 1) {
        int add = (tid >= off && tid < 128) ? excl[tid - off] : 0;
        __syncthreads();
        if (tid < 128) excl[tid] += add;
        __syncthreads();
    }
    if (tid < BKT) {
        Row[b * BKT + tid] = s + excl[tid];
        cur[tid] = excl[tid];
    }
    if (b == 0 && tid == 0) Row[NNODES] = NEDGES;
    __syncthreads();
    for (int i = tid; i < n; i += 256) {
        int v = BktE[s + i];
        int tl = ((unsigned)v) >> 24;
        int p = atomicAdd(&cur[tl], 1);
        CsrSrc[s + p] = v & 0xFFFFFF;
    }
}

// ---------- aggregation: target-aligned chunks, register accumulate ----------
__global__ __launch_bounds__(256) void agg_k(const __hip_bfloat16* __restrict__ Ps,
                                             const __hip_bfloat16* __restrict__ Pt,
                                             const int* __restrict__ Row,
                                             const int* __restrict__ CsrSrc,
                                             __hip_bfloat16* __restrict__ Msg) {
    const int lane = threadIdx.x & 63;
    const int wib = __builtin_amdgcn_readfirstlane(threadIdx.x >> 6);
    const int w = blockIdx.x * 4 + wib;
    if (w >= NCHUNK) return;
    const int eA = w * CHUNK;
    const int hiB = (w == NCHUNK - 1) ? (NEDGES + 1) : (eA + CHUNK);

    int lo = 0, hi = NNODES + 1;
    while (lo < hi) { int mid = (lo + hi) >> 1; if (Row[mid] >= eA) hi = mid; else lo = mid + 1; }
    const int t_lo = lo;
    lo = t_lo; hi = NNODES + 1;
    while (lo < hi) { int mid = (lo + hi) >> 1; if (Row[mid] >= hiB) hi = mid; else lo = mid + 1; }
    int t_hi = lo;
    if (t_hi > NNODES) t_hi = NNODES;

    const unsigned short* Ps16 = (const unsigned short*)Ps;
    const unsigned short* Pt16 = (const unsigned short*)Pt;

    for (int t = t_lo; t < t_hi; ++t) {
        const int segS = Row[t], segE = Row[t + 1];
        const int deg = segE - segS;
        float pt = bf2f(Pt16[(size_t)t * DF + lane]);
        float macc = 0.f;
        int i = segS;
        for (; i + 8 <= segE; i += 8) {
            int s0 = CsrSrc[i+0], s1 = CsrSrc[i+1], s2 = CsrSrc[i+2], s3 = CsrSrc[i+3];
            int s4 = CsrSrc[i+4], s5 = CsrSrc[i+5], s6 = CsrSrc[i+6], s7 = CsrSrc[i+7];
            if ((unsigned)s0 >= NNODES) s0 = 0;
            if ((unsigned)s1 >= NNODES) s1 = 0;
            if ((unsigned)s2 >= NNODES) s2 = 0;
            if ((unsigned)s3 >= NNODES) s3 = 0;
            if ((unsigned)s4 >= NNODES) s4 = 0;
            if ((unsigned)s5 >= NNODES) s5 = 0;
            if ((unsigned)s6 >= NNODES) s6 = 0;
            if ((unsigned)s7 >= NNODES) s7 = 0;
            float p0 = bf2f(Ps16[(size_t)s0 * DF + lane]);
            float p1 = bf2f(Ps16[(size_t)s1 * DF + lane]);
            float p2 = bf2f(Ps16[(size_t)s2 * DF + lane]);
            float p3 = bf2f(Ps16[(size_t)s3 * DF + lane]);
            float p4 = bf2f(Ps16[(size_t)s4 * DF + lane]);
            float p5 = bf2f(Ps16[(size_t)s5 * DF + lane]);
            float p6 = bf2f(Ps16[(size_t)s6 * DF + lane]);
            float p7 = bf2f(Ps16[(size_t)s7 * DF + lane]);
            macc += fmaxf(p0 + pt, 0.f) + fmaxf(p1 + pt, 0.f)
                  + fmaxf(p2 + pt, 0.f) + fmaxf(p3 + pt, 0.f)
                  + fmaxf(p4 + pt, 0.f) + fmaxf(p5 + pt, 0.f)
                  + fmaxf(p6 + pt, 0.f) + fmaxf(p7 + pt, 0.f);
        }
        for (; i < segE; ++i) {
            int s0 = CsrSrc[i];
            if ((unsigned)s0 >= NNODES) s0 = 0;
            macc += fmaxf(bf2f(Ps16[(size_t)s0 * DF + lane]) + pt, 0.f);
        }
        float mval = (deg > 0) ? (macc / (float)deg) : 0.f;
        Msg[(size_t)t * DF + lane] = __float2bfloat16(mval);
    }
}

// ---------- update via MFMA + fused bias/relu/residual/LayerNorm ----------
// bf16 path: wave = 16 nodes, 4 coltiles, K=128 over [x | Msg] vs raw W_upd rows.
__global__ __launch_bounds__(256) void upd_k(const int* __restrict__ flags,
                                             const void* __restrict__ xv,
                                             const __hip_bfloat16* __restrict__ Msg,
                                             const void* __restrict__ WuRaw,
                                             const float* __restrict__ WfU,
                                             const float* __restrict__ prm,
                                             void* __restrict__ outv) {
    const int bf = flags[0];
    const int lane = threadIdx.x & 63;
    const int wib = __builtin_amdgcn_readfirstlane(threadIdx.x >> 6);

    if (bf) {
        const int w = blockIdx.x * 4 + wib;
        if (w >= NWTILE) return;
        const int node0 = w * 16;
        const int m = lane & 15, quad = lane >> 4;
        const unsigned short* x16 = (const unsigned short*)xv;
        const unsigned short* mg16 = (const unsigned short*)Msg;
        const unsigned short* wu16 = (const unsigned short*)WuRaw;

        const short8 Ax0 = *(const short8*)(x16 + (size_t)(node0 + m) * 64 + quad * 8);
        const short8 Ax1 = *(const short8*)(x16 + (size_t)(node0 + m) * 64 + 32 + quad * 8);
        const short8 Am0 = *(const short8*)(mg16 + (size_t)(node0 + m) * 64 + quad * 8);
        const short8 Am1 = *(const short8*)(mg16 + (size_t)(node0 + m) * 64 + 32 + quad * 8);

        float v[4][4];   // [coltile][reg]
        #pragma unroll
        for (int c = 0; c < 4; ++c) {
            const int j = c * 16 + m;   // W_upd row = out feature
            const short8 B0 = *(const short8*)(wu16 + j * 128 + quad * 8);
            const short8 B1 = *(const short8*)(wu16 + j * 128 + 32 + quad * 8);
            const short8 B2 = *(const short8*)(wu16 + j * 128 + 64 + quad * 8);
            const short8 B3 = *(const short8*)(wu16 + j * 128 + 96 + quad * 8);
            f32x4 acc = {0.f, 0.f, 0.f, 0.f};
            acc = __builtin_amdgcn_mfma_f32_16x16x32_bf16(Ax0, B0, acc, 0, 0, 0);
            acc = __builtin_amdgcn_mfma_f32_16x16x32_bf16(Ax1, B1, acc, 0, 0, 0);
            acc = __builtin_amdgcn_mfma_f32_16x16x32_bf16(Am0, B2, acc, 0, 0, 0);
            acc = __builtin_amdgcn_mfma_f32_16x16x32_bf16(Am1, B3, acc, 0, 0, 0);
            const int colg = c * 16 + m;
            const float buc = prm[64 + colg];
            #pragma unroll
            for (int r = 0; r < 4; ++r) {
                const int node = node0 + quad * 4 + r;
                const float xl = bf2f(x16[(size_t)node * 64 + colg]);  // L1-hot
                v[c][r] = fmaxf(acc[r] + buc, 0.f) + xl;
            }
        }

        // LayerNorm: node (quad,r)'s 64 features live in 16 lanes (quad group) x 4 tiles
        float o_mu[4], o_rs[4];
        #pragma unroll
        for (int r = 0; r < 4; ++r) {
            float s  = v[0][r] + v[1][r] + v[2][r] + v[3][r];
            float s2 = v[0][r]*v[0][r] + v[1][r]*v[1][r] + v[2][r]*v[2][r] + v[3][r]*v[3][r];
            #pragma unroll
            for (int msk = 1; msk < 16; msk <<= 1) {
                s  += __shfl_xor(s,  msk, 64);
                s2 += __shfl_xor(s2, msk, 64);
            }
            const float mu  = s * (1.0f / 64.0f);
            const float var = fmaxf(s2 * (1.0f / 64.0f) - mu * mu, 0.f);
            o_mu[r] = mu;
            o_rs[r] = rsqrtf(var + 1e-5f);
        }

        __hip_bfloat16* o16 = (__hip_bfloat16*)outv;
        #pragma unroll
        for (int c = 0; c < 4; ++c) {
            const int colg = c * 16 + m;
            const float gac = prm[128 + colg];
            const float bec = prm[192 + colg];
            #pragma unroll
            for (int r = 0; r < 4; ++r) {
                const int node = node0 + quad * 4 + r;
                o16[(size_t)node * 64 + colg] =
                    __float2bfloat16((v[c][r] - o_mu[r]) * o_rs[r] * gac + bec);
            }
        }
    } else {
        // fp32 fallback (VALU)
        float wx[64], wm[64];
        const float* r0 = WfU + lane * 64;
        const float* r1 = WfU + (lane + 64) * 64;
        #pragma unroll
        for (int k = 0; k < 64; ++k) { wx[k] = r0[k]; wm[k] = r1[k]; }
        const float bu = prm[64 + lane];
        const float ga = prm[128 + lane];
        const float be = prm[192 + lane];
        for (int n = blockIdx.x * 4 + wib; n < NNODES; n += gridDim.x * 4) {
            float da = 0.f, db = 0.f;
            const float* xf = (const float*)xv + (size_t)n * DF;
            const uint32_t* mw = (const uint32_t*)((const unsigned short*)Msg + (size_t)n * DF);
            #pragma unroll
            for (int d = 0; d < 32; ++d) {
                float m0, m1; unpack2(mw[d], m0, m1);
                da = fmaf(xf[2*d],   wx[2*d],   da);
                da = fmaf(xf[2*d+1], wx[2*d+1], da);
                db = fmaf(m0, wm[2*d],   db);
                db = fmaf(m1, wm[2*d+1], db);
            }
            float xl = xf[lane];
            float u = fmaxf(da + db + bu, 0.f);
            float r = u + xl;
            float s = r, s2 = r * r;
            #pragma unroll
            for (int msk = 1; msk < 64; msk <<= 1) {
                s  += __shfl_xor(s,  msk, 64);
                s2 += __shfl_xor(s2, msk, 64);
            }
            float mu  = s * (1.0f / 64.0f);
            float var = fmaxf(s2 * (1.0f / 64.0f) - mu * mu, 0.f);
            ((float*)outv)[(size_t)n * DF + lane] = (r - mu) * rsqrtf(var + 1e-5f) * ga + be;
        }
    }
}

extern "C" void kernel_launch(void* const* d_in, const int* in_sizes, int n_in,
                              void* d_out, int out_size, void* d_ws, size_t ws_size,
                              hipStream_t stream) {
    const void* x  = d_in[0];
    const int*  ei = (const int*)d_in[1];
    const void* Wm = d_in[2];
    const void* bm = d_in[3];
    const void* Wu = d_in[4];
    const void* bu = d_in[5];
    const void* ga = d_in[6];
    const void* be = d_in[7];

    char* ws = (char*)d_ws;
    size_t off = 0;
    __hip_bfloat16* Ps  = (__hip_bfloat16*)(ws + off); off += (size_t)ND * 2;   // 12.8 MB
    __hip_bfloat16* Pt  = (__hip_bfloat16*)(ws + off); off += (size_t)ND * 2;   // 12.8 MB
    __hip_bfloat16* Msg = (__hip_bfloat16*)(ws + off); off += (size_t)ND * 2;   // 12.8 MB
    int*   BktE   = (int*)(ws + off); off += (size_t)NEDGES * 4;                // 6.4 MB
    int*   CsrSrc = (int*)(ws + off); off += (size_t)NEDGES * 4;                // 6.4 MB
    int*   Row    = (int*)(ws + off); off += (size_t)(NNODES + 1) * 4;
    int*   BktCnt = (int*)(ws + off); off += NBUCK * 4;                         // memset 0
    int*   BktOff = (int*)(ws + off); off += (NBUCK + 1) * 4;
    int*   BktCur = (int*)(ws + off); off += NBUCK * 4;
    int*   flg    = (int*)(ws + off); off += 16;
    float* WfM    = (float*)(ws + off); off += 8192 * 4;
    float* WfU    = (float*)(ws + off); off += 8192 * 4;
    float* prm    = (float*)(ws + off); off += 256 * 4;

    (void)hipMemsetAsync(BktCnt, 0, NBUCK * 4, stream);

    detect_k<<<1, 256, 0, stream>>>((const unsigned short*)x, (const unsigned int*)ei, flg);
    wconv_k<<<65, 256, 0, stream>>>(flg, Wm, Wu, bm, bu, ga, be, WfM, WfU, prm);

    proj_k<<<1563, 256, 0, stream>>>(flg, x, Wm, WfM, prm, Ps, Pt);

    bhist_k<<<256, 256, 0, stream>>>(flg, ei, BktCnt);
    bscan_k<<<1, 1024, 0, stream>>>(BktCnt, BktOff, BktCur);
    bfill_k<<<128, 256, 0, stream>>>(flg, ei, BktCur, BktE);
    tsort_k<<<NBUCK, 256, 0, stream>>>(BktOff, BktE, CsrSrc, Row);

    agg_k<<<(NCHUNK + 3) / 4, 256, 0, stream>>>(Ps, Pt, Row, CsrSrc, Msg);

    upd_k<<<1563, 256, 0, stream>>>(flg, x, Msg, Wu, WfU, prm, d_out);
}